// Round 3
// baseline (364.130 us; speedup 1.0000x reference)
//
#include <hip/hip_runtime.h>
#include <hip/hip_bf16.h>

#define BB  4
#define HH  128
#define WW  128
#define CC  192
#define NHH 6
#define KDD 32
#define NTOT (BB*HH*WW*CC)   // 12582912
#define SCALING 0.17677669529663687f

typedef __hip_bfloat16 bf16;
typedef short bf16x8 __attribute__((ext_vector_type(8)));
typedef unsigned short ushortx4 __attribute__((ext_vector_type(4)));
typedef float floatx4 __attribute__((ext_vector_type(4)));

__device__ __forceinline__ float b2f(bf16 v) { return __bfloat162float(v); }
__device__ __forceinline__ bf16  f2b(float v) { return __float2bfloat16(v); }
__device__ __forceinline__ unsigned short f2bs(float f) {
  union { bf16 b; unsigned short u; } c; c.b = __float2bfloat16(f); return c.u;
}
__device__ __forceinline__ float s2f(short s) {
  union { unsigned u; float f; } c;
  c.u = ((unsigned)(unsigned short)s) << 16; return c.f;
}

// ---------------- K0: weight prep — transpose fp32 W -> bf16 Wt[n][k] -------
// Wt order: Wq | Wk(*SCALING) | Wv | Wo, each 192x192.
__global__ __launch_bounds__(256) void prep_kernel(
    const float* __restrict__ Wq, const float* __restrict__ Wk,
    const float* __restrict__ Wv, const float* __restrict__ Wo,
    unsigned short* __restrict__ Wt) {
  const int idx = blockIdx.x * 256 + threadIdx.x;   // 4*36864 total
  if (idx >= 4 * CC * CC) return;
  const int mat = idx / (CC * CC);
  const int rem = idx % (CC * CC);
  const int kk = rem / CC;
  const int nn = rem % CC;
  const float* W = (mat == 0) ? Wq : (mat == 1) ? Wk : (mat == 2) ? Wv : Wo;
  float val = W[kk * CC + nn];
  if (mat == 1) val *= SCALING;
  Wt[mat * CC * CC + nn * CC + kk] = f2bs(val);
}

// ---------------- K1: QKV projection via MFMA (q,k,v all bf16) --------------
// v4: 2 row-fragments per wave (32 rows), 3 matrices fused, nt range split
// in half across 2 blocks -> 4096 waves (4/SIMD, ~50% occupancy) while
// keeping 2-chain ILP per W-load. x rows are re-read by the second half
// (L3-resident fp32, cheap) in exchange for 2x TLP to hide L2 load latency.
__global__ __launch_bounds__(256) void qkv_mfma(
    const float* __restrict__ x, const unsigned short* __restrict__ Wt,
    const float* __restrict__ bq, const float* __restrict__ bk,
    const float* __restrict__ bv,
    bf16* __restrict__ q, bf16* __restrict__ k, bf16* __restrict__ v) {
  const int wave = threadIdx.x >> 6, l = threadIdx.x & 63;
  const int r16 = l & 15, quad = l >> 4;
  const int half = blockIdx.x & 1;                  // nt 0..5 | 6..11
  const int row0 = (blockIdx.x >> 1) * 128 + wave * 32;   // wave covers 32 rows
  const floatx4 zero = {0.f, 0.f, 0.f, 0.f};
  bf16x8 a[2][6];
  #pragma unroll
  for (int rs = 0; rs < 2; ++rs) {
    const float* xrow = x + (row0 + rs * 16 + r16) * CC;
    #pragma unroll
    for (int kc = 0; kc < 6; ++kc) {
      const float4* p = reinterpret_cast<const float4*>(xrow + kc * 32 + quad * 8);
      float4 u0 = p[0], u1 = p[1];
      bf16x8 t;
      t[0]=f2bs(u0.x); t[1]=f2bs(u0.y); t[2]=f2bs(u0.z); t[3]=f2bs(u0.w);
      t[4]=f2bs(u1.x); t[5]=f2bs(u1.y); t[6]=f2bs(u1.z); t[7]=f2bs(u1.w);
      a[rs][kc] = t;
    }
  }
  #pragma unroll
  for (int mat = 0; mat < 3; ++mat) {
    const unsigned short* Wm = Wt + mat * CC * CC;
    bf16* outp = (mat == 0) ? q : (mat == 1) ? k : v;
    const float* bias = (mat == 0) ? bq : (mat == 1) ? bk : bv;
    const float bscale = (mat == 1) ? SCALING : 1.f;
    #pragma unroll
    for (int t = 0; t < 6; ++t) {
      const int nt = half * 6 + t;
      bf16x8 wfr[6];
      #pragma unroll
      for (int kc = 0; kc < 6; ++kc)
        wfr[kc] = *reinterpret_cast<const bf16x8*>(
            Wm + (nt * 16 + r16) * CC + kc * 32 + quad * 8);
      floatx4 acc0 = zero, acc1 = zero;
      #pragma unroll
      for (int kc = 0; kc < 6; ++kc) {
        acc0 = __builtin_amdgcn_mfma_f32_16x16x32_bf16(wfr[kc], a[0][kc], acc0, 0, 0, 0);
        acc1 = __builtin_amdgcn_mfma_f32_16x16x32_bf16(wfr[kc], a[1][kc], acc1, 0, 0, 0);
      }
      const int col0 = nt * 16 + quad * 4;
      const float4 b4 = *reinterpret_cast<const float4*>(bias + col0);
      ushortx4 s0, s1;
      s0[0] = f2bs(acc0[0] + b4.x * bscale);
      s0[1] = f2bs(acc0[1] + b4.y * bscale);
      s0[2] = f2bs(acc0[2] + b4.z * bscale);
      s0[3] = f2bs(acc0[3] + b4.w * bscale);
      s1[0] = f2bs(acc1[0] + b4.x * bscale);
      s1[1] = f2bs(acc1[1] + b4.y * bscale);
      s1[2] = f2bs(acc1[2] + b4.z * bscale);
      s1[3] = f2bs(acc1[3] + b4.w * bscale);
      *reinterpret_cast<ushortx4*>(&outp[(row0 + r16) * CC + col0]) = s0;
      *reinterpret_cast<ushortx4*>(&outp[(row0 + 16 + r16) * CC + col0]) = s1;
    }
  }
}

// ---------------- K2: depthwise 5x5 conv (LEPE), 8 channels/thread ----------
__global__ __launch_bounds__(256) void lepe_kernel(
    const bf16* __restrict__ v, const float* __restrict__ kw,
    const float* __restrict__ kb, float* __restrict__ lepe) {
  const int tid = blockIdx.x * 256 + threadIdx.x;    // NTOT/8 threads
  const int c8 = tid % (CC / 8);
  const int w  = (tid / (CC / 8)) % WW;
  const int h  = (tid / ((CC / 8) * WW)) % HH;
  const int b  = tid / ((CC / 8) * WW * HH);
  const int c0 = c8 * 8;
  float acc[8];
  {
    const float4* kbp = reinterpret_cast<const float4*>(kb + c0);
    float4 b0 = kbp[0], b1 = kbp[1];
    acc[0]=b0.x; acc[1]=b0.y; acc[2]=b0.z; acc[3]=b0.w;
    acc[4]=b1.x; acc[5]=b1.y; acc[6]=b1.z; acc[7]=b1.w;
  }
  #pragma unroll
  for (int kh = 0; kh < 5; ++kh) {
    const int hh = h + kh - 2;
    if ((unsigned)hh >= HH) continue;
    #pragma unroll
    for (int kwi = 0; kwi < 5; ++kwi) {
      const int ww = w + kwi - 2;
      if ((unsigned)ww >= WW) continue;
      bf16x8 vv = *reinterpret_cast<const bf16x8*>(
          v + ((b * HH + hh) * WW + ww) * CC + c0);
      const float4* kp = reinterpret_cast<const float4*>(
          kw + (kh * 5 + kwi) * CC + c0);
      float4 k0 = kp[0], k1 = kp[1];
      acc[0] = fmaf(s2f(vv[0]), k0.x, acc[0]);
      acc[1] = fmaf(s2f(vv[1]), k0.y, acc[1]);
      acc[2] = fmaf(s2f(vv[2]), k0.z, acc[2]);
      acc[3] = fmaf(s2f(vv[3]), k0.w, acc[3]);
      acc[4] = fmaf(s2f(vv[4]), k1.x, acc[4]);
      acc[5] = fmaf(s2f(vv[5]), k1.y, acc[5]);
      acc[6] = fmaf(s2f(vv[6]), k1.z, acc[6]);
      acc[7] = fmaf(s2f(vv[7]), k1.w, acc[7]);
    }
  }
  float4* op = reinterpret_cast<float4*>(lepe + ((b * HH + h) * WW + w) * CC + c0);
  op[0] = make_float4(acc[0], acc[1], acc[2], acc[3]);
  op[1] = make_float4(acc[4], acc[5], acc[6], acc[7]);
}

// ---------------- K3/K4: MFMA attention (row or column axis) ----------------
__global__ __launch_bounds__(64) void attn_mfma_kernel(
    const bf16* __restrict__ qg, const bf16* __restrict__ kg,
    bf16* vbuf, const float* __restrict__ mask,
    const float* __restrict__ lepeadd, const int rstride, const int is_col) {
  __shared__ unsigned short P[16 * 136];
  const int bx = blockIdx.x;
  const int n = bx % NHH;
  const int p = (bx / NHH) % 128;
  const int b = bx / (NHH * 128);
  const int base = is_col ? ((b * HH * WW + p) * CC + n * KDD)
                          : (((b * HH + p) * WW) * CC + n * KDD);
  const int l = threadIdx.x;
  const int r16 = l & 15, quad = l >> 4;
  const float* mbase = mask + n * 128 * 128;
  const floatx4 zero = {0.f, 0.f, 0.f, 0.f};
  const short* vs = (const short*)vbuf;

  bf16x8 kf[8];
  #pragma unroll
  for (int ni = 0; ni < 8; ++ni) {
    kf[ni] = *reinterpret_cast<const bf16x8*>(
        kg + base + (ni * 16 + r16) * rstride + quad * 8);
  }
  bf16x8 vf[4][2];
  #pragma unroll
  for (int s = 0; s < 4; ++s) {
    #pragma unroll
    for (int nj = 0; nj < 2; ++nj) {
      bf16x8 t;
      #pragma unroll
      for (int j = 0; j < 8; ++j) {
        const int key = s * 32 + quad * 8 + j;
        t[j] = vs[base + key * rstride + nj * 16 + r16];
      }
      vf[s][nj] = t;
    }
  }

  for (int mi = 0; mi < 8; ++mi) {
    bf16x8 qf = *reinterpret_cast<const bf16x8*>(
        qg + base + (mi * 16 + r16) * rstride + quad * 8);
    floatx4 S[8];
    #pragma unroll
    for (int ni = 0; ni < 8; ++ni)
      S[ni] = __builtin_amdgcn_mfma_f32_16x16x32_bf16(qf, kf[ni], zero, 0, 0, 0);
    #pragma unroll
    for (int ni = 0; ni < 8; ++ni)
      #pragma unroll
      for (int i = 0; i < 4; ++i)
        S[ni][i] += mbase[(mi * 16 + quad * 4 + i) * 128 + ni * 16 + r16];
    float linv[4], mrow[4];
    #pragma unroll
    for (int i = 0; i < 4; ++i) {
      float m = S[0][i];
      #pragma unroll
      for (int ni = 1; ni < 8; ++ni) m = fmaxf(m, S[ni][i]);
      m = fmaxf(m, __shfl_xor(m, 1));
      m = fmaxf(m, __shfl_xor(m, 2));
      m = fmaxf(m, __shfl_xor(m, 4));
      m = fmaxf(m, __shfl_xor(m, 8));
      mrow[i] = m;
    }
    #pragma unroll
    for (int i = 0; i < 4; ++i) {
      float lsum = 0.f;
      #pragma unroll
      for (int ni = 0; ni < 8; ++ni) {
        const float pv = __expf(S[ni][i] - mrow[i]);
        S[ni][i] = pv;
        lsum += pv;
      }
      lsum += __shfl_xor(lsum, 1);
      lsum += __shfl_xor(lsum, 2);
      lsum += __shfl_xor(lsum, 4);
      lsum += __shfl_xor(lsum, 8);
      linv[i] = 1.f / lsum;
    }
    #pragma unroll
    for (int ni = 0; ni < 8; ++ni)
      #pragma unroll
      for (int i = 0; i < 4; ++i)
        P[(quad * 4 + i) * 136 + ni * 16 + r16] = f2bs(S[ni][i] * linv[i]);
    floatx4 O[2] = {zero, zero};
    #pragma unroll
    for (int s = 0; s < 4; ++s) {
      bf16x8 pf = *reinterpret_cast<const bf16x8*>(
          &P[r16 * 136 + s * 32 + quad * 8]);
      #pragma unroll
      for (int nj = 0; nj < 2; ++nj)
        O[nj] = __builtin_amdgcn_mfma_f32_16x16x32_bf16(pf, vf[s][nj], O[nj], 0, 0, 0);
    }
    #pragma unroll
    for (int nj = 0; nj < 2; ++nj)
      #pragma unroll
      for (int i = 0; i < 4; ++i) {
        const int addr = base + (mi * 16 + quad * 4 + i) * rstride + nj * 16 + r16;
        float val = O[nj][i];
        if (lepeadd) val += lepeadd[addr];
        vbuf[addr] = f2b(val);
      }
  }
}

// ---------------- K5: output projection via MFMA (bf16 pre -> fp32 out) -----
// v4: 2 row-fragments per wave (32 rows), nt halves split across 2 blocks
// for TLP, operand-swapped MFMA -> single float4 store per rowset.
__global__ __launch_bounds__(256) void proj_mfma(
    const bf16* __restrict__ pre, const unsigned short* __restrict__ Wto,
    const float* __restrict__ bo, float* __restrict__ out) {
  const int wave = threadIdx.x >> 6, l = threadIdx.x & 63;
  const int r16 = l & 15, quad = l >> 4;
  const int half = blockIdx.x & 1;                  // nt 0..5 | 6..11
  const int row0 = (blockIdx.x >> 1) * 128 + wave * 32;
  const floatx4 zero = {0.f, 0.f, 0.f, 0.f};
  bf16x8 a[2][6];
  #pragma unroll
  for (int rs = 0; rs < 2; ++rs)
    #pragma unroll
    for (int kc = 0; kc < 6; ++kc)
      a[rs][kc] = *reinterpret_cast<const bf16x8*>(
          pre + (row0 + rs * 16 + r16) * CC + kc * 32 + quad * 8);
  #pragma unroll
  for (int t = 0; t < 6; ++t) {
    const int nt = half * 6 + t;
    bf16x8 wfr[6];
    #pragma unroll
    for (int kc = 0; kc < 6; ++kc)
      wfr[kc] = *reinterpret_cast<const bf16x8*>(
          Wto + (nt * 16 + r16) * CC + kc * 32 + quad * 8);
    floatx4 acc0 = zero, acc1 = zero;
    #pragma unroll
    for (int kc = 0; kc < 6; ++kc) {
      acc0 = __builtin_amdgcn_mfma_f32_16x16x32_bf16(wfr[kc], a[0][kc], acc0, 0, 0, 0);
      acc1 = __builtin_amdgcn_mfma_f32_16x16x32_bf16(wfr[kc], a[1][kc], acc1, 0, 0, 0);
    }
    const int col0 = nt * 16 + quad * 4;
    const float4 b4 = *reinterpret_cast<const float4*>(bo + col0);
    float4 s0 = make_float4(acc0[0] + b4.x, acc0[1] + b4.y,
                            acc0[2] + b4.z, acc0[3] + b4.w);
    float4 s1 = make_float4(acc1[0] + b4.x, acc1[1] + b4.y,
                            acc1[2] + b4.z, acc1[3] + b4.w);
    *reinterpret_cast<float4*>(&out[(row0 + r16) * CC + col0]) = s0;
    *reinterpret_cast<float4*>(&out[(row0 + 16 + r16) * CC + col0]) = s1;
  }
}

extern "C" void kernel_launch(void* const* d_in, const int* in_sizes, int n_in,
                              void* d_out, int out_size, void* d_ws, size_t ws_size,
                              hipStream_t stream) {
  const float* x      = (const float*)d_in[0];
  const float* mask_h = (const float*)d_in[1];
  const float* mask_w = (const float*)d_in[2];
  const float* Wq = (const float*)d_in[3];
  const float* bq = (const float*)d_in[4];
  const float* Wk = (const float*)d_in[5];
  const float* bk = (const float*)d_in[6];
  const float* Wv = (const float*)d_in[7];
  const float* bv = (const float*)d_in[8];
  const float* lw = (const float*)d_in[9];
  const float* lb = (const float*)d_in[10];
  const float* Wo = (const float*)d_in[11];
  const float* bo = (const float*)d_in[12];
  float* out = (float*)d_out;

  // ws: q bf16 | k bf16 | v bf16 (each NTOT) | Wt bf16 4x192x192 = 75.8 MB
  bf16* q    = (bf16*)d_ws;
  bf16* kbuf = q + NTOT;
  bf16* v    = kbuf + NTOT;
  unsigned short* Wt = (unsigned short*)(v + NTOT);

  prep_kernel<<<(4*CC*CC + 255)/256, 256, 0, stream>>>(Wq, Wk, Wv, Wo, Wt);
  qkv_mfma<<<2 * (BB*HH*WW)/128, 256, 0, stream>>>(x, Wt, bq, bk, bv, q, kbuf, v);
  lepe_kernel<<<(NTOT/8 + 255)/256, 256, 0, stream>>>(v, lw, lb, out);  // out = lepe
  attn_mfma_kernel<<<BB*128*NHH, 64, 0, stream>>>(
      q, kbuf, v, mask_w, nullptr, CC, 0);                  // v := v1
  attn_mfma_kernel<<<BB*128*NHH, 64, 0, stream>>>(
      q, kbuf, v, mask_h, out, WW*CC, 1);                   // v := attn+lepe
  proj_mfma<<<2 * (BB*HH*WW)/128, 256, 0, stream>>>(v, Wt + 3*CC*CC, bo, out);
}

// Round 4
// 326.455 us; speedup vs baseline: 1.1154x; 1.1154x over previous
//
#include <hip/hip_runtime.h>
#include <hip/hip_bf16.h>

#define BB  4
#define HH  128
#define WW  128
#define CC  192
#define NHH 6
#define KDD 32
#define NTOT (BB*HH*WW*CC)   // 12582912
#define SCALING 0.17677669529663687f
#define WMAT_ELE (12*6*64*8)   // 36864 bf16 elements per matrix, fragment order

typedef __hip_bfloat16 bf16;
typedef short bf16x8 __attribute__((ext_vector_type(8)));
typedef unsigned short ushortx4 __attribute__((ext_vector_type(4)));
typedef float floatx4 __attribute__((ext_vector_type(4)));

__device__ __forceinline__ float b2f(bf16 v) { return __bfloat162float(v); }
__device__ __forceinline__ bf16  f2b(float v) { return __float2bfloat16(v); }
__device__ __forceinline__ unsigned short f2bs(float f) {
  union { bf16 b; unsigned short u; } c; c.b = __float2bfloat16(f); return c.u;
}
__device__ __forceinline__ float s2f(short s) {
  union { unsigned u; float f; } c;
  c.u = ((unsigned)(unsigned short)s) << 16; return c.f;
}

// ---------------- K0: weight prep — fp32 W -> bf16 fragment-order Wt --------
// Wt[mat][nt][kc][lane][j] = W[kc*32 + (lane>>4)*8 + j][nt*16 + (lane&15)]
// (mat order: Wq | Wk*SCALING | Wv | Wo). This makes (a) LDS staging a pure
// linear lane-contiguous copy and (b) ds_read_b128 of a fragment = base +
// lane*16B -> bank-conflict-free with zero swizzle.
__global__ __launch_bounds__(256) void prep_kernel(
    const float* __restrict__ Wq, const float* __restrict__ Wk,
    const float* __restrict__ Wv, const float* __restrict__ Wo,
    unsigned short* __restrict__ Wt) {
  const int idx = blockIdx.x * 256 + threadIdx.x;   // 4*12*6*64 = 18432
  if (idx >= 4 * 12 * 6 * 64) return;
  const int lane = idx & 63;
  int rest = idx >> 6;
  const int kc = rest % 6; rest /= 6;
  const int nt = rest % 12;
  const int mat = rest / 12;
  const int r16 = lane & 15, quad = lane >> 4;
  const float* W = (mat == 0) ? Wq : (mat == 1) ? Wk : (mat == 2) ? Wv : Wo;
  const float sc = (mat == 1) ? SCALING : 1.f;
  bf16x8 t;
  #pragma unroll
  for (int j = 0; j < 8; ++j)
    t[j] = (short)f2bs(W[(kc * 32 + quad * 8 + j) * CC + nt * 16 + r16] * sc);
  *reinterpret_cast<bf16x8*>(&Wt[(size_t)idx * 8]) = t;
}

// ---------------- K1: QKV projection via MFMA, W staged in LDS --------------
// v5: W-fragment loads were suffering ~5000-cyc L2-evicted latency (x/qkv
// streams thrash the 4MB per-XCD L2). Stage each half-matrix (36 KB) into
// LDS once per block; compute reads via conflict-free ds_read_b128.
// Block: 256 thr / 4 waves, 128 rows, all 3 mats, all 12 nt. 36 KB LDS ->
// 4 blocks/CU. 2 rowsets/wave keep 2-chain MFMA ILP per fragment.
__global__ __launch_bounds__(256) void qkv_mfma(
    const float* __restrict__ x, const unsigned short* __restrict__ Wt,
    const float* __restrict__ bq, const float* __restrict__ bk,
    const float* __restrict__ bv,
    bf16* __restrict__ q, bf16* __restrict__ k, bf16* __restrict__ v) {
  __shared__ __align__(16) unsigned short Wlds[18432];   // 36 KB: 6nt x 6kc x 64 x 8
  const int tid = threadIdx.x;
  const int l = tid & 63;
  const int r16 = l & 15, quad = l >> 4;
  const int row0 = blockIdx.x * 128 + (tid >> 6) * 32;   // wave covers 32 rows
  const floatx4 zero = {0.f, 0.f, 0.f, 0.f};
  bf16x8 a[2][6];
  #pragma unroll
  for (int rs = 0; rs < 2; ++rs) {
    const float* xrow = x + (row0 + rs * 16 + r16) * CC;
    #pragma unroll
    for (int kc = 0; kc < 6; ++kc) {
      const float4* p = reinterpret_cast<const float4*>(xrow + kc * 32 + quad * 8);
      float4 u0 = p[0], u1 = p[1];
      bf16x8 t;
      t[0]=f2bs(u0.x); t[1]=f2bs(u0.y); t[2]=f2bs(u0.z); t[3]=f2bs(u0.w);
      t[4]=f2bs(u1.x); t[5]=f2bs(u1.y); t[6]=f2bs(u1.z); t[7]=f2bs(u1.w);
      a[rs][kc] = t;
    }
  }
  for (int mat = 0; mat < 3; ++mat) {
    const unsigned short* Wm = Wt + mat * WMAT_ELE;
    bf16* outp = (mat == 0) ? q : (mat == 1) ? k : v;
    const float* bias = (mat == 0) ? bq : (mat == 1) ? bk : bv;
    const float bscale = (mat == 1) ? SCALING : 1.f;
    for (int hf = 0; hf < 2; ++hf) {
      __syncthreads();   // previous half fully consumed before overwrite
      #pragma unroll
      for (int c = 0; c < 9; ++c) {          // 36 KB = 256 thr x 9 x 16 B
        const int ci = c * 256 + tid;
        *reinterpret_cast<bf16x8*>(&Wlds[ci * 8]) =
            *reinterpret_cast<const bf16x8*>(&Wm[hf * 18432 + ci * 8]);
      }
      __syncthreads();
      #pragma unroll
      for (int ntl = 0; ntl < 6; ++ntl) {
        const int nt = hf * 6 + ntl;
        bf16x8 wfr[6];
        #pragma unroll
        for (int kc = 0; kc < 6; ++kc)
          wfr[kc] = *reinterpret_cast<const bf16x8*>(
              &Wlds[((ntl * 6 + kc) * 64 + l) * 8]);
        floatx4 acc0 = zero, acc1 = zero;
        #pragma unroll
        for (int kc = 0; kc < 6; ++kc) {
          acc0 = __builtin_amdgcn_mfma_f32_16x16x32_bf16(wfr[kc], a[0][kc], acc0, 0, 0, 0);
          acc1 = __builtin_amdgcn_mfma_f32_16x16x32_bf16(wfr[kc], a[1][kc], acc1, 0, 0, 0);
        }
        const int col0 = nt * 16 + quad * 4;
        const float4 b4 = *reinterpret_cast<const float4*>(bias + col0);
        ushortx4 s0, s1;
        s0[0] = f2bs(acc0[0] + b4.x * bscale);
        s0[1] = f2bs(acc0[1] + b4.y * bscale);
        s0[2] = f2bs(acc0[2] + b4.z * bscale);
        s0[3] = f2bs(acc0[3] + b4.w * bscale);
        s1[0] = f2bs(acc1[0] + b4.x * bscale);
        s1[1] = f2bs(acc1[1] + b4.y * bscale);
        s1[2] = f2bs(acc1[2] + b4.z * bscale);
        s1[3] = f2bs(acc1[3] + b4.w * bscale);
        *reinterpret_cast<ushortx4*>(&outp[(row0 + r16) * CC + col0]) = s0;
        *reinterpret_cast<ushortx4*>(&outp[(row0 + 16 + r16) * CC + col0]) = s1;
      }
    }
  }
}

// ---------------- K2: depthwise 5x5 conv (LEPE), 8 channels/thread ----------
__global__ __launch_bounds__(256) void lepe_kernel(
    const bf16* __restrict__ v, const float* __restrict__ kw,
    const float* __restrict__ kb, float* __restrict__ lepe) {
  const int tid = blockIdx.x * 256 + threadIdx.x;    // NTOT/8 threads
  const int c8 = tid % (CC / 8);
  const int w  = (tid / (CC / 8)) % WW;
  const int h  = (tid / ((CC / 8) * WW)) % HH;
  const int b  = tid / ((CC / 8) * WW * HH);
  const int c0 = c8 * 8;
  float acc[8];
  {
    const float4* kbp = reinterpret_cast<const float4*>(kb + c0);
    float4 b0 = kbp[0], b1 = kbp[1];
    acc[0]=b0.x; acc[1]=b0.y; acc[2]=b0.z; acc[3]=b0.w;
    acc[4]=b1.x; acc[5]=b1.y; acc[6]=b1.z; acc[7]=b1.w;
  }
  #pragma unroll
  for (int kh = 0; kh < 5; ++kh) {
    const int hh = h + kh - 2;
    if ((unsigned)hh >= HH) continue;
    #pragma unroll
    for (int kwi = 0; kwi < 5; ++kwi) {
      const int ww = w + kwi - 2;
      if ((unsigned)ww >= WW) continue;
      bf16x8 vv = *reinterpret_cast<const bf16x8*>(
          v + ((b * HH + hh) * WW + ww) * CC + c0);
      const float4* kp = reinterpret_cast<const float4*>(
          kw + (kh * 5 + kwi) * CC + c0);
      float4 k0 = kp[0], k1 = kp[1];
      acc[0] = fmaf(s2f(vv[0]), k0.x, acc[0]);
      acc[1] = fmaf(s2f(vv[1]), k0.y, acc[1]);
      acc[2] = fmaf(s2f(vv[2]), k0.z, acc[2]);
      acc[3] = fmaf(s2f(vv[3]), k0.w, acc[3]);
      acc[4] = fmaf(s2f(vv[4]), k1.x, acc[4]);
      acc[5] = fmaf(s2f(vv[5]), k1.y, acc[5]);
      acc[6] = fmaf(s2f(vv[6]), k1.z, acc[6]);
      acc[7] = fmaf(s2f(vv[7]), k1.w, acc[7]);
    }
  }
  float4* op = reinterpret_cast<float4*>(lepe + ((b * HH + h) * WW + w) * CC + c0);
  op[0] = make_float4(acc[0], acc[1], acc[2], acc[3]);
  op[1] = make_float4(acc[4], acc[5], acc[6], acc[7]);
}

// ---------------- K3/K4: MFMA attention (row or column axis) ----------------
__global__ __launch_bounds__(64) void attn_mfma_kernel(
    const bf16* __restrict__ qg, const bf16* __restrict__ kg,
    bf16* vbuf, const float* __restrict__ mask,
    const float* __restrict__ lepeadd, const int rstride, const int is_col) {
  __shared__ unsigned short P[16 * 136];
  const int bx = blockIdx.x;
  const int n = bx % NHH;
  const int p = (bx / NHH) % 128;
  const int b = bx / (NHH * 128);
  const int base = is_col ? ((b * HH * WW + p) * CC + n * KDD)
                          : (((b * HH + p) * WW) * CC + n * KDD);
  const int l = threadIdx.x;
  const int r16 = l & 15, quad = l >> 4;
  const float* mbase = mask + n * 128 * 128;
  const floatx4 zero = {0.f, 0.f, 0.f, 0.f};
  const short* vs = (const short*)vbuf;

  bf16x8 kf[8];
  #pragma unroll
  for (int ni = 0; ni < 8; ++ni) {
    kf[ni] = *reinterpret_cast<const bf16x8*>(
        kg + base + (ni * 16 + r16) * rstride + quad * 8);
  }
  bf16x8 vf[4][2];
  #pragma unroll
  for (int s = 0; s < 4; ++s) {
    #pragma unroll
    for (int nj = 0; nj < 2; ++nj) {
      bf16x8 t;
      #pragma unroll
      for (int j = 0; j < 8; ++j) {
        const int key = s * 32 + quad * 8 + j;
        t[j] = vs[base + key * rstride + nj * 16 + r16];
      }
      vf[s][nj] = t;
    }
  }

  for (int mi = 0; mi < 8; ++mi) {
    bf16x8 qf = *reinterpret_cast<const bf16x8*>(
        qg + base + (mi * 16 + r16) * rstride + quad * 8);
    floatx4 S[8];
    #pragma unroll
    for (int ni = 0; ni < 8; ++ni)
      S[ni] = __builtin_amdgcn_mfma_f32_16x16x32_bf16(qf, kf[ni], zero, 0, 0, 0);
    #pragma unroll
    for (int ni = 0; ni < 8; ++ni)
      #pragma unroll
      for (int i = 0; i < 4; ++i)
        S[ni][i] += mbase[(mi * 16 + quad * 4 + i) * 128 + ni * 16 + r16];
    float linv[4], mrow[4];
    #pragma unroll
    for (int i = 0; i < 4; ++i) {
      float m = S[0][i];
      #pragma unroll
      for (int ni = 1; ni < 8; ++ni) m = fmaxf(m, S[ni][i]);
      m = fmaxf(m, __shfl_xor(m, 1));
      m = fmaxf(m, __shfl_xor(m, 2));
      m = fmaxf(m, __shfl_xor(m, 4));
      m = fmaxf(m, __shfl_xor(m, 8));
      mrow[i] = m;
    }
    #pragma unroll
    for (int i = 0; i < 4; ++i) {
      float lsum = 0.f;
      #pragma unroll
      for (int ni = 0; ni < 8; ++ni) {
        const float pv = __expf(S[ni][i] - mrow[i]);
        S[ni][i] = pv;
        lsum += pv;
      }
      lsum += __shfl_xor(lsum, 1);
      lsum += __shfl_xor(lsum, 2);
      lsum += __shfl_xor(lsum, 4);
      lsum += __shfl_xor(lsum, 8);
      linv[i] = 1.f / lsum;
    }
    #pragma unroll
    for (int ni = 0; ni < 8; ++ni)
      #pragma unroll
      for (int i = 0; i < 4; ++i)
        P[(quad * 4 + i) * 136 + ni * 16 + r16] = f2bs(S[ni][i] * linv[i]);
    floatx4 O[2] = {zero, zero};
    #pragma unroll
    for (int s = 0; s < 4; ++s) {
      bf16x8 pf = *reinterpret_cast<const bf16x8*>(
          &P[r16 * 136 + s * 32 + quad * 8]);
      #pragma unroll
      for (int nj = 0; nj < 2; ++nj)
        O[nj] = __builtin_amdgcn_mfma_f32_16x16x32_bf16(pf, vf[s][nj], O[nj], 0, 0, 0);
    }
    #pragma unroll
    for (int nj = 0; nj < 2; ++nj)
      #pragma unroll
      for (int i = 0; i < 4; ++i) {
        const int addr = base + (mi * 16 + quad * 4 + i) * rstride + nj * 16 + r16;
        float val = O[nj][i];
        if (lepeadd) val += lepeadd[addr];
        vbuf[addr] = f2b(val);
      }
  }
}

// ---------------- K5: output projection via MFMA, Wo staged in LDS ----------
__global__ __launch_bounds__(256) void proj_mfma(
    const bf16* __restrict__ pre, const unsigned short* __restrict__ Wto,
    const float* __restrict__ bo, float* __restrict__ out) {
  __shared__ __align__(16) unsigned short Wlds[18432];   // 36 KB
  const int tid = threadIdx.x;
  const int l = tid & 63;
  const int r16 = l & 15, quad = l >> 4;
  const int row0 = blockIdx.x * 128 + (tid >> 6) * 32;
  const floatx4 zero = {0.f, 0.f, 0.f, 0.f};
  bf16x8 a[2][6];
  #pragma unroll
  for (int rs = 0; rs < 2; ++rs)
    #pragma unroll
    for (int kc = 0; kc < 6; ++kc)
      a[rs][kc] = *reinterpret_cast<const bf16x8*>(
          pre + (row0 + rs * 16 + r16) * CC + kc * 32 + quad * 8);
  for (int hf = 0; hf < 2; ++hf) {
    __syncthreads();
    #pragma unroll
    for (int c = 0; c < 9; ++c) {
      const int ci = c * 256 + tid;
      *reinterpret_cast<bf16x8*>(&Wlds[ci * 8]) =
          *reinterpret_cast<const bf16x8*>(&Wto[hf * 18432 + ci * 8]);
    }
    __syncthreads();
    #pragma unroll
    for (int ntl = 0; ntl < 6; ++ntl) {
      const int nt = hf * 6 + ntl;
      bf16x8 wfr[6];
      #pragma unroll
      for (int kc = 0; kc < 6; ++kc)
        wfr[kc] = *reinterpret_cast<const bf16x8*>(
            &Wlds[((ntl * 6 + kc) * 64 + l) * 8]);
      floatx4 acc0 = zero, acc1 = zero;
      #pragma unroll
      for (int kc = 0; kc < 6; ++kc) {
        acc0 = __builtin_amdgcn_mfma_f32_16x16x32_bf16(wfr[kc], a[0][kc], acc0, 0, 0, 0);
        acc1 = __builtin_amdgcn_mfma_f32_16x16x32_bf16(wfr[kc], a[1][kc], acc1, 0, 0, 0);
      }
      const int col0 = nt * 16 + quad * 4;
      const float4 b4 = *reinterpret_cast<const float4*>(bo + col0);
      float4 s0 = make_float4(acc0[0] + b4.x, acc0[1] + b4.y,
                              acc0[2] + b4.z, acc0[3] + b4.w);
      float4 s1 = make_float4(acc1[0] + b4.x, acc1[1] + b4.y,
                              acc1[2] + b4.z, acc1[3] + b4.w);
      *reinterpret_cast<float4*>(&out[(row0 + r16) * CC + col0]) = s0;
      *reinterpret_cast<float4*>(&out[(row0 + 16 + r16) * CC + col0]) = s1;
    }
  }
}

extern "C" void kernel_launch(void* const* d_in, const int* in_sizes, int n_in,
                              void* d_out, int out_size, void* d_ws, size_t ws_size,
                              hipStream_t stream) {
  const float* x      = (const float*)d_in[0];
  const float* mask_h = (const float*)d_in[1];
  const float* mask_w = (const float*)d_in[2];
  const float* Wq = (const float*)d_in[3];
  const float* bq = (const float*)d_in[4];
  const float* Wk = (const float*)d_in[5];
  const float* bk = (const float*)d_in[6];
  const float* Wv = (const float*)d_in[7];
  const float* bv = (const float*)d_in[8];
  const float* lw = (const float*)d_in[9];
  const float* lb = (const float*)d_in[10];
  const float* Wo = (const float*)d_in[11];
  const float* bo = (const float*)d_in[12];
  float* out = (float*)d_out;

  // ws: q bf16 | k bf16 | v bf16 (each NTOT) | Wt bf16 4x36864 = 75.8 MB
  bf16* q    = (bf16*)d_ws;
  bf16* kbuf = q + NTOT;
  bf16* v    = kbuf + NTOT;
  unsigned short* Wt = (unsigned short*)(v + NTOT);

  prep_kernel<<<(4*12*6*64 + 255)/256, 256, 0, stream>>>(Wq, Wk, Wv, Wo, Wt);
  qkv_mfma<<<(BB*HH*WW)/128, 256, 0, stream>>>(x, Wt, bq, bk, bv, q, kbuf, v);
  lepe_kernel<<<(NTOT/8 + 255)/256, 256, 0, stream>>>(v, lw, lb, out);  // out = lepe
  attn_mfma_kernel<<<BB*128*NHH, 64, 0, stream>>>(
      q, kbuf, v, mask_w, nullptr, CC, 0);                  // v := v1
  attn_mfma_kernel<<<BB*128*NHH, 64, 0, stream>>>(
      q, kbuf, v, mask_h, out, WW*CC, 1);                   // v := attn+lepe
  proj_mfma<<<(BB*HH*WW)/128, 256, 0, stream>>>(v, Wt + 3*WMAT_ELE, bo, out);
}

// Round 6
// 325.356 us; speedup vs baseline: 1.1192x; 1.0034x over previous
//
#include <hip/hip_runtime.h>
#include <hip/hip_bf16.h>

#define BB  4
#define HH  128
#define WW  128
#define CC  192
#define NHH 6
#define KDD 32
#define NTOT (BB*HH*WW*CC)   // 12582912
#define SCALING 0.17677669529663687f
#define WMAT_ELE (12*6*64*8)   // 36864 bf16 elements per matrix, fragment order

typedef __hip_bfloat16 bf16;
typedef short bf16x8 __attribute__((ext_vector_type(8)));
typedef unsigned short ushortx4 __attribute__((ext_vector_type(4)));
typedef float floatx4 __attribute__((ext_vector_type(4)));

__device__ __forceinline__ float b2f(bf16 v) { return __bfloat162float(v); }
__device__ __forceinline__ bf16  f2b(float v) { return __float2bfloat16(v); }
__device__ __forceinline__ unsigned short f2bs(float f) {
  union { bf16 b; unsigned short u; } c; c.b = __float2bfloat16(f); return c.u;
}
__device__ __forceinline__ float s2f(short s) {
  union { unsigned u; float f; } c;
  c.u = ((unsigned)(unsigned short)s) << 16; return c.f;
}

// ---------------- K0: weight prep — fp32 W -> bf16 fragment-order Wt --------
// Wt[mat][nt][kc][lane][j] = W[kc*32 + (lane>>4)*8 + j][nt*16 + (lane&15)]
// (mat order: Wq | Wk*SCALING | Wv | Wo). This makes (a) LDS staging a pure
// linear lane-contiguous copy and (b) ds_read_b128 of a fragment = base +
// lane*16B -> bank-conflict-free with zero swizzle.
__global__ __launch_bounds__(256) void prep_kernel(
    const float* __restrict__ Wq, const float* __restrict__ Wk,
    const float* __restrict__ Wv, const float* __restrict__ Wo,
    unsigned short* __restrict__ Wt) {
  const int idx = blockIdx.x * 256 + threadIdx.x;   // 4*12*6*64 = 18432
  if (idx >= 4 * 12 * 6 * 64) return;
  const int lane = idx & 63;
  int rest = idx >> 6;
  const int kc = rest % 6; rest /= 6;
  const int nt = rest % 12;
  const int mat = rest / 12;
  const int r16 = lane & 15, quad = lane >> 4;
  const float* W = (mat == 0) ? Wq : (mat == 1) ? Wk : (mat == 2) ? Wv : Wo;
  const float sc = (mat == 1) ? SCALING : 1.f;
  bf16x8 t;
  #pragma unroll
  for (int j = 0; j < 8; ++j)
    t[j] = (short)f2bs(W[(kc * 32 + quad * 8 + j) * CC + nt * 16 + r16] * sc);
  *reinterpret_cast<bf16x8*>(&Wt[(size_t)idx * 8]) = t;
}

// ---------------- K1: QKV projection via MFMA, W staged in LDS --------------
__global__ __launch_bounds__(256) void qkv_mfma(
    const float* __restrict__ x, const unsigned short* __restrict__ Wt,
    const float* __restrict__ bq, const float* __restrict__ bk,
    const float* __restrict__ bv,
    bf16* __restrict__ q, bf16* __restrict__ k, bf16* __restrict__ v) {
  __shared__ __align__(16) unsigned short Wlds[18432];   // 36 KB: 6nt x 6kc x 64 x 8
  const int tid = threadIdx.x;
  const int l = tid & 63;
  const int r16 = l & 15, quad = l >> 4;
  const int row0 = blockIdx.x * 128 + (tid >> 6) * 32;   // wave covers 32 rows
  const floatx4 zero = {0.f, 0.f, 0.f, 0.f};
  bf16x8 a[2][6];
  #pragma unroll
  for (int rs = 0; rs < 2; ++rs) {
    const float* xrow = x + (row0 + rs * 16 + r16) * CC;
    #pragma unroll
    for (int kc = 0; kc < 6; ++kc) {
      const float4* p = reinterpret_cast<const float4*>(xrow + kc * 32 + quad * 8);
      float4 u0 = p[0], u1 = p[1];
      bf16x8 t;
      t[0]=f2bs(u0.x); t[1]=f2bs(u0.y); t[2]=f2bs(u0.z); t[3]=f2bs(u0.w);
      t[4]=f2bs(u1.x); t[5]=f2bs(u1.y); t[6]=f2bs(u1.z); t[7]=f2bs(u1.w);
      a[rs][kc] = t;
    }
  }
  for (int mat = 0; mat < 3; ++mat) {
    const unsigned short* Wm = Wt + mat * WMAT_ELE;
    bf16* outp = (mat == 0) ? q : (mat == 1) ? k : v;
    const float* bias = (mat == 0) ? bq : (mat == 1) ? bk : bv;
    const float bscale = (mat == 1) ? SCALING : 1.f;
    for (int hf = 0; hf < 2; ++hf) {
      __syncthreads();   // previous half fully consumed before overwrite
      #pragma unroll
      for (int c = 0; c < 9; ++c) {          // 36 KB = 256 thr x 9 x 16 B
        const int ci = c * 256 + tid;
        *reinterpret_cast<bf16x8*>(&Wlds[ci * 8]) =
            *reinterpret_cast<const bf16x8*>(&Wm[hf * 18432 + ci * 8]);
      }
      __syncthreads();
      #pragma unroll
      for (int ntl = 0; ntl < 6; ++ntl) {
        const int nt = hf * 6 + ntl;
        bf16x8 wfr[6];
        #pragma unroll
        for (int kc = 0; kc < 6; ++kc)
          wfr[kc] = *reinterpret_cast<const bf16x8*>(
              &Wlds[((ntl * 6 + kc) * 64 + l) * 8]);
        floatx4 acc0 = zero, acc1 = zero;
        #pragma unroll
        for (int kc = 0; kc < 6; ++kc) {
          acc0 = __builtin_amdgcn_mfma_f32_16x16x32_bf16(wfr[kc], a[0][kc], acc0, 0, 0, 0);
          acc1 = __builtin_amdgcn_mfma_f32_16x16x32_bf16(wfr[kc], a[1][kc], acc1, 0, 0, 0);
        }
        const int col0 = nt * 16 + quad * 4;
        const float4 b4 = *reinterpret_cast<const float4*>(bias + col0);
        ushortx4 s0, s1;
        s0[0] = f2bs(acc0[0] + b4.x * bscale);
        s0[1] = f2bs(acc0[1] + b4.y * bscale);
        s0[2] = f2bs(acc0[2] + b4.z * bscale);
        s0[3] = f2bs(acc0[3] + b4.w * bscale);
        s1[0] = f2bs(acc1[0] + b4.x * bscale);
        s1[1] = f2bs(acc1[1] + b4.y * bscale);
        s1[2] = f2bs(acc1[2] + b4.z * bscale);
        s1[3] = f2bs(acc1[3] + b4.w * bscale);
        *reinterpret_cast<ushortx4*>(&outp[(row0 + r16) * CC + col0]) = s0;
        *reinterpret_cast<ushortx4*>(&outp[(row0 + 16 + r16) * CC + col0]) = s1;
      }
    }
  }
}

// ---------------- K2: depthwise 5x5 conv (LEPE), 8 channels/thread ----------
// v2: VGPR=20 showed the compiler serialized the 25 tap loads (each ~250cyc
// L1/L2 latency fully exposed -> 6660 cyc/wave measured). Batch ALL 25 tap
// loads into registers first (OOB taps zero-filled -> adds exact 0*k), then
// run the 200 FMAs. One pipelined load burst instead of 25 exposed stalls.
__global__ __launch_bounds__(256) void lepe_kernel(
    const bf16* __restrict__ v, const float* __restrict__ kw,
    const float* __restrict__ kb, float* __restrict__ lepe) {
  const int tid = blockIdx.x * 256 + threadIdx.x;    // NTOT/8 threads
  const int c8 = tid % (CC / 8);
  const int w  = (tid / (CC / 8)) % WW;
  const int h  = (tid / ((CC / 8) * WW)) % HH;
  const int b  = tid / ((CC / 8) * WW * HH);
  const int c0 = c8 * 8;
  const bf16x8 vzero = {0, 0, 0, 0, 0, 0, 0, 0};
  // phase 1: batch-load all 25 taps (predicated, zero-filled OOB)
  bf16x8 vv[25];
  #pragma unroll
  for (int kh = 0; kh < 5; ++kh) {
    const int hh = h + kh - 2;
    #pragma unroll
    for (int kwi = 0; kwi < 5; ++kwi) {
      const int ww = w + kwi - 2;
      bf16x8 t = vzero;
      if ((unsigned)hh < HH && (unsigned)ww < WW)
        t = *reinterpret_cast<const bf16x8*>(
            v + ((b * HH + hh) * WW + ww) * CC + c0);
      vv[kh * 5 + kwi] = t;
    }
  }
  // phase 2: accumulate
  float acc[8];
  {
    const float4* kbp = reinterpret_cast<const float4*>(kb + c0);
    float4 b0 = kbp[0], b1 = kbp[1];
    acc[0]=b0.x; acc[1]=b0.y; acc[2]=b0.z; acc[3]=b0.w;
    acc[4]=b1.x; acc[5]=b1.y; acc[6]=b1.z; acc[7]=b1.w;
  }
  #pragma unroll
  for (int tap = 0; tap < 25; ++tap) {
    const float4* kp = reinterpret_cast<const float4*>(kw + tap * CC + c0);
    float4 k0 = kp[0], k1 = kp[1];
    const bf16x8 t = vv[tap];
    acc[0] = fmaf(s2f(t[0]), k0.x, acc[0]);
    acc[1] = fmaf(s2f(t[1]), k0.y, acc[1]);
    acc[2] = fmaf(s2f(t[2]), k0.z, acc[2]);
    acc[3] = fmaf(s2f(t[3]), k0.w, acc[3]);
    acc[4] = fmaf(s2f(t[4]), k1.x, acc[4]);
    acc[5] = fmaf(s2f(t[5]), k1.y, acc[5]);
    acc[6] = fmaf(s2f(t[6]), k1.z, acc[6]);
    acc[7] = fmaf(s2f(t[7]), k1.w, acc[7]);
  }
  float4* op = reinterpret_cast<float4*>(lepe + ((b * HH + h) * WW + w) * CC + c0);
  op[0] = make_float4(acc[0], acc[1], acc[2], acc[3]);
  op[1] = make_float4(acc[4], acc[5], acc[6], acc[7]);
}

// ---------------- K3/K4: MFMA attention (row or column axis) ----------------
__global__ __launch_bounds__(64) void attn_mfma_kernel(
    const bf16* __restrict__ qg, const bf16* __restrict__ kg,
    bf16* vbuf, const float* __restrict__ mask,
    const float* __restrict__ lepeadd, const int rstride, const int is_col) {
  __shared__ unsigned short P[16 * 136];
  const int bx = blockIdx.x;
  const int n = bx % NHH;
  const int p = (bx / NHH) % 128;
  const int b = bx / (NHH * 128);
  const int base = is_col ? ((b * HH * WW + p) * CC + n * KDD)
                          : (((b * HH + p) * WW) * CC + n * KDD);
  const int l = threadIdx.x;
  const int r16 = l & 15, quad = l >> 4;
  const float* mbase = mask + n * 128 * 128;
  const floatx4 zero = {0.f, 0.f, 0.f, 0.f};
  const short* vs = (const short*)vbuf;

  bf16x8 kf[8];
  #pragma unroll
  for (int ni = 0; ni < 8; ++ni) {
    kf[ni] = *reinterpret_cast<const bf16x8*>(
        kg + base + (ni * 16 + r16) * rstride + quad * 8);
  }
  bf16x8 vf[4][2];
  #pragma unroll
  for (int s = 0; s < 4; ++s) {
    #pragma unroll
    for (int nj = 0; nj < 2; ++nj) {
      bf16x8 t;
      #pragma unroll
      for (int j = 0; j < 8; ++j) {
        const int key = s * 32 + quad * 8 + j;
        t[j] = vs[base + key * rstride + nj * 16 + r16];
      }
      vf[s][nj] = t;
    }
  }

  for (int mi = 0; mi < 8; ++mi) {
    bf16x8 qf = *reinterpret_cast<const bf16x8*>(
        qg + base + (mi * 16 + r16) * rstride + quad * 8);
    floatx4 S[8];
    #pragma unroll
    for (int ni = 0; ni < 8; ++ni)
      S[ni] = __builtin_amdgcn_mfma_f32_16x16x32_bf16(qf, kf[ni], zero, 0, 0, 0);
    #pragma unroll
    for (int ni = 0; ni < 8; ++ni)
      #pragma unroll
      for (int i = 0; i < 4; ++i)
        S[ni][i] += mbase[(mi * 16 + quad * 4 + i) * 128 + ni * 16 + r16];
    float linv[4], mrow[4];
    #pragma unroll
    for (int i = 0; i < 4; ++i) {
      float m = S[0][i];
      #pragma unroll
      for (int ni = 1; ni < 8; ++ni) m = fmaxf(m, S[ni][i]);
      m = fmaxf(m, __shfl_xor(m, 1));
      m = fmaxf(m, __shfl_xor(m, 2));
      m = fmaxf(m, __shfl_xor(m, 4));
      m = fmaxf(m, __shfl_xor(m, 8));
      mrow[i] = m;
    }
    #pragma unroll
    for (int i = 0; i < 4; ++i) {
      float lsum = 0.f;
      #pragma unroll
      for (int ni = 0; ni < 8; ++ni) {
        const float pv = __expf(S[ni][i] - mrow[i]);
        S[ni][i] = pv;
        lsum += pv;
      }
      lsum += __shfl_xor(lsum, 1);
      lsum += __shfl_xor(lsum, 2);
      lsum += __shfl_xor(lsum, 4);
      lsum += __shfl_xor(lsum, 8);
      linv[i] = 1.f / lsum;
    }
    #pragma unroll
    for (int ni = 0; ni < 8; ++ni)
      #pragma unroll
      for (int i = 0; i < 4; ++i)
        P[(quad * 4 + i) * 136 + ni * 16 + r16] = f2bs(S[ni][i] * linv[i]);
    floatx4 O[2] = {zero, zero};
    #pragma unroll
    for (int s = 0; s < 4; ++s) {
      bf16x8 pf = *reinterpret_cast<const bf16x8*>(
          &P[r16 * 136 + s * 32 + quad * 8]);
      #pragma unroll
      for (int nj = 0; nj < 2; ++nj)
        O[nj] = __builtin_amdgcn_mfma_f32_16x16x32_bf16(pf, vf[s][nj], O[nj], 0, 0, 0);
    }
    #pragma unroll
    for (int nj = 0; nj < 2; ++nj)
      #pragma unroll
      for (int i = 0; i < 4; ++i) {
        const int addr = base + (mi * 16 + quad * 4 + i) * rstride + nj * 16 + r16;
        float val = O[nj][i];
        if (lepeadd) val += lepeadd[addr];
        vbuf[addr] = f2b(val);
      }
  }
}

// ---------------- K5: output projection via MFMA, Wo staged in LDS ----------
__global__ __launch_bounds__(256) void proj_mfma(
    const bf16* __restrict__ pre, const unsigned short* __restrict__ Wto,
    const float* __restrict__ bo, float* __restrict__ out) {
  __shared__ __align__(16) unsigned short Wlds[18432];   // 36 KB
  const int tid = threadIdx.x;
  const int l = tid & 63;
  const int r16 = l & 15, quad = l >> 4;
  const int row0 = blockIdx.x * 128 + (tid >> 6) * 32;
  const floatx4 zero = {0.f, 0.f, 0.f, 0.f};
  bf16x8 a[2][6];
  #pragma unroll
  for (int rs = 0; rs < 2; ++rs)
    #pragma unroll
    for (int kc = 0; kc < 6; ++kc)
      a[rs][kc] = *reinterpret_cast<const bf16x8*>(
          pre + (row0 + rs * 16 + r16) * CC + kc * 32 + quad * 8);
  for (int hf = 0; hf < 2; ++hf) {
    __syncthreads();
    #pragma unroll
    for (int c = 0; c < 9; ++c) {
      const int ci = c * 256 + tid;
      *reinterpret_cast<bf16x8*>(&Wlds[ci * 8]) =
          *reinterpret_cast<const bf16x8*>(&Wto[hf * 18432 + ci * 8]);
    }
    __syncthreads();
    #pragma unroll
    for (int ntl = 0; ntl < 6; ++ntl) {
      const int nt = hf * 6 + ntl;
      bf16x8 wfr[6];
      #pragma unroll
      for (int kc = 0; kc < 6; ++kc)
        wfr[kc] = *reinterpret_cast<const bf16x8*>(
            &Wlds[((ntl * 6 + kc) * 64 + l) * 8]);
      floatx4 acc0 = zero, acc1 = zero;
      #pragma unroll
      for (int kc = 0; kc < 6; ++kc) {
        acc0 = __builtin_amdgcn_mfma_f32_16x16x32_bf16(wfr[kc], a[0][kc], acc0, 0, 0, 0);
        acc1 = __builtin_amdgcn_mfma_f32_16x16x32_bf16(wfr[kc], a[1][kc], acc1, 0, 0, 0);
      }
      const int col0 = nt * 16 + quad * 4;
      const float4 b4 = *reinterpret_cast<const float4*>(bo + col0);
      float4 s0 = make_float4(acc0[0] + b4.x, acc0[1] + b4.y,
                              acc0[2] + b4.z, acc0[3] + b4.w);
      float4 s1 = make_float4(acc1[0] + b4.x, acc1[1] + b4.y,
                              acc1[2] + b4.z, acc1[3] + b4.w);
      *reinterpret_cast<float4*>(&out[(row0 + r16) * CC + col0]) = s0;
      *reinterpret_cast<float4*>(&out[(row0 + 16 + r16) * CC + col0]) = s1;
    }
  }
}

extern "C" void kernel_launch(void* const* d_in, const int* in_sizes, int n_in,
                              void* d_out, int out_size, void* d_ws, size_t ws_size,
                              hipStream_t stream) {
  const float* x      = (const float*)d_in[0];
  const float* mask_h = (const float*)d_in[1];
  const float* mask_w = (const float*)d_in[2];
  const float* Wq = (const float*)d_in[3];
  const float* bq = (const float*)d_in[4];
  const float* Wk = (const float*)d_in[5];
  const float* bk = (const float*)d_in[6];
  const float* Wv = (const float*)d_in[7];
  const float* bv = (const float*)d_in[8];
  const float* lw = (const float*)d_in[9];
  const float* lb = (const float*)d_in[10];
  const float* Wo = (const float*)d_in[11];
  const float* bo = (const float*)d_in[12];
  float* out = (float*)d_out;

  // ws: q bf16 | k bf16 | v bf16 (each NTOT) | Wt bf16 4x36864 = 75.8 MB
  bf16* q    = (bf16*)d_ws;
  bf16* kbuf = q + NTOT;
  bf16* v    = kbuf + NTOT;
  unsigned short* Wt = (unsigned short*)(v + NTOT);

  prep_kernel<<<(4*12*6*64 + 255)/256, 256, 0, stream>>>(Wq, Wk, Wv, Wo, Wt);
  qkv_mfma<<<(BB*HH*WW)/128, 256, 0, stream>>>(x, Wt, bq, bk, bv, q, kbuf, v);
  lepe_kernel<<<(NTOT/8 + 255)/256, 256, 0, stream>>>(v, lw, lb, out);  // out = lepe
  attn_mfma_kernel<<<BB*128*NHH, 64, 0, stream>>>(
      q, kbuf, v, mask_w, nullptr, CC, 0);                  // v := v1
  attn_mfma_kernel<<<BB*128*NHH, 64, 0, stream>>>(
      q, kbuf, v, mask_h, out, WW*CC, 1);                   // v := attn+lepe
  proj_mfma<<<(BB*HH*WW)/128, 256, 0, stream>>>(v, Wt + 3*WMAT_ELE, bo, out);
}